// Round 11
// baseline (159.522 us; speedup 1.0000x reference)
//
#include <hip/hip_runtime.h>
#include <hip/hip_bf16.h>
#include <math.h>

// Problem constants (B=1)
#define SEQ   2048
#define HID   1024
#define NH    16
#define HD    64
#define WIN   128
#define GSTR  64

typedef __attribute__((ext_vector_type(8))) short short8;   // 8 bf16 = 4 VGPRs
typedef __attribute__((ext_vector_type(4))) float f32x4;    // MFMA C/D
typedef unsigned short ushort_t;

// RNE fp32 -> bf16 bits (finite inputs)
__device__ inline unsigned short bf16b(float f) {
    union { float f; unsigned int u; } v; v.f = f;
    return (unsigned short)((v.u + 0x7FFFu + ((v.u >> 16) & 1u)) >> 16);
}
// bf16 (low/high ushort of a uint) -> fp32
__device__ inline float blo(unsigned int u) {
    union { unsigned int i; float f; } v; v.i = u << 16; return v.f;
}
__device__ inline float bhi(unsigned int u) {
    union { unsigned int i; float f; } v; v.i = u & 0xFFFF0000u; return v.f;
}

#define GLOAD_LDS16(gp, lp)                                                    \
    __builtin_amdgcn_global_load_lds(                                          \
        (const __attribute__((address_space(1))) unsigned int*)(gp),           \
        (__attribute__((address_space(3))) unsigned int*)(lp), 16, 0, 0)

// ---------------------------------------------------------------------------
// fp32 -> bf16 pre-convert of x, Wqkv, Wout
// ---------------------------------------------------------------------------
__global__ __launch_bounds__(256) void cvt_bf16(const float4* __restrict__ x,
                                                const float4* __restrict__ wq,
                                                const float4* __restrict__ wo,
                                                ushort4* __restrict__ x16,
                                                ushort4* __restrict__ wq16,
                                                ushort4* __restrict__ wo16) {
    for (int idx = blockIdx.x * 256 + threadIdx.x; idx < 1572864;
         idx += gridDim.x * 256) {
        const float4* src; ushort4* dst; int off;
        if (idx < 524288)       { src = x;  dst = x16;  off = idx; }
        else if (idx < 1310720) { src = wq; dst = wq16; off = idx - 524288; }
        else                    { src = wo; dst = wo16; off = idx - 1310720; }
        float4 v = src[off];
        ushort4 o;
        o.x = bf16b(v.x); o.y = bf16b(v.y); o.z = bf16b(v.z); o.w = bf16b(v.w);
        dst[off] = o;
    }
}

// ---------------------------------------------------------------------------
// m97-style MFMA GEMM: C[M,N] = A[M,K] @ B[N,K]^T, bf16 in, fp32 acc.
// Tile BM x BN, BK=32, 256 threads (4 waves, 2x2 wave grid). (unchanged R10)
// ---------------------------------------------------------------------------
template <int BM, int BN, typename OT>
__global__ __launch_bounds__(256) void gemm_bt16(const unsigned short* __restrict__ A,
                                                 const unsigned short* __restrict__ B,
                                                 OT* __restrict__ C,
                                                 int M, int N, int K) {
    constexpr int MI = BM / 32;
    constexpr int NJ = BN / 32;
    __shared__ unsigned short As[BM * 32];
    __shared__ unsigned short Bs[BN * 32];

    const int tid  = threadIdx.x;
    const int wave = tid >> 6;
    const int lane = tid & 63;
    const int quad = lane >> 4;
    const int l15  = lane & 15;
    const int bm = blockIdx.y * BM;
    const int bn = blockIdx.x * BN;
    const int wm = (wave & 1) * (BM / 2);
    const int wn = (wave >> 1) * (BN / 2);
    const int srow = lane >> 2;
    const int scol = (lane & 3) * 8;

    f32x4 acc[MI][NJ];
    #pragma unroll
    for (int i = 0; i < MI; ++i)
        #pragma unroll
        for (int j = 0; j < NJ; ++j)
            acc[i][j] = (f32x4){0.f, 0.f, 0.f, 0.f};

    for (int k0 = 0; k0 < K; k0 += 32) {
        #pragma unroll
        for (int t = 0; t < BM / 64; ++t) {
            const int row = wave * (BM / 4) + t * 16 + srow;
            GLOAD_LDS16(A + (size_t)(bm + row) * K + k0 + scol,
                        &As[(size_t)row * 32 + scol]);
        }
        #pragma unroll
        for (int t = 0; t < BN / 64; ++t) {
            const int row = wave * (BN / 4) + t * 16 + srow;
            GLOAD_LDS16(B + (size_t)(bn + row) * K + k0 + scol,
                        &Bs[(size_t)row * 32 + scol]);
        }
        __syncthreads();

        short8 a[MI], b[NJ];
        #pragma unroll
        for (int im = 0; im < MI; ++im)
            a[im] = *(const short8*)&As[(wm + im * 16 + l15) * 32 + quad * 8];
        #pragma unroll
        for (int jn = 0; jn < NJ; ++jn)
            b[jn] = *(const short8*)&Bs[(wn + jn * 16 + l15) * 32 + quad * 8];

        #pragma unroll
        for (int im = 0; im < MI; ++im)
            #pragma unroll
            for (int jn = 0; jn < NJ; ++jn)
                acc[im][jn] = __builtin_amdgcn_mfma_f32_16x16x32_bf16(
                    a[im], b[jn], acc[im][jn], 0, 0, 0);
        __syncthreads();
    }

    #pragma unroll
    for (int im = 0; im < MI; ++im)
        #pragma unroll
        for (int jn = 0; jn < NJ; ++jn)
            #pragma unroll
            for (int reg = 0; reg < 4; ++reg) {
                const int r = bm + wm + im * 16 + quad * 4 + reg;
                const int c = bn + wn + jn * 16 + l15;
                float v = acc[im][jn][reg];
                if constexpr (sizeof(OT) == 2)
                    C[(size_t)r * N + c] = (OT)bf16b(v);
                else
                    C[(size_t)r * N + c] = (OT)v;
            }
}

// ---------------------------------------------------------------------------
// Fused attention. qkv16: [SEQ][3*HID] bf16; aout16: [SEQ][HID] bf16.
// blockIdx.x < 64: banded+gather, 32 queries/block, KEY-SPLIT 2-way:
//   wave w: query-group qg=w&1 (16 queries via l15), key-split ks=w>>1.
//   Tile list = [t0g..t1g window tiles, gather]; pair ks=0 takes the first
//   n0=ceil(ntot/2) (all window), ks=1 the rest (incl. gather). Per step both
//   pairs' tiles staged cooperatively, then each wave computes its tile with
//   private (m,l,O). 2-way merge via LDS at the end (global-path pattern).
//   Grid 1024+32 blocks = 4.1/CU (vs 2.1) -> TLP for the latency chains.
// blockIdx.x in {64,65}: global rows, MFMA flash-decoding (unchanged).
// ---------------------------------------------------------------------------
__global__ __launch_bounds__(256) void attn_fused(const unsigned short* __restrict__ qkv16,
                                                  unsigned short* __restrict__ aout16) {
    __shared__ __align__(16) unsigned char smem[50688];
    const int tid = threadIdx.x;
    const int h = blockIdx.y;
    const int w    = tid >> 6;
    const int lane = tid & 63;
    const int quad = lane >> 4;
    const int l15  = lane & 15;

    if (blockIdx.x < 64) {
        // ----------------- banded path (32-q tiles, key-split) --------------
        ushort_t* Qs  = (ushort_t*)smem;                       // [32][72] 4608
        ushort_t* Kb0 = (ushort_t*)(smem + 4608);              // [64][72] 9216
        ushort_t* Kb1 = (ushort_t*)(smem + 13824);             // [64][72]
        ushort_t* Vb0 = (ushort_t*)(smem + 23040);             // [64][72]
        ushort_t* Vb1 = (ushort_t*)(smem + 32256);             // [64][72]
        ushort_t* Psw = (ushort_t*)(smem + 41472 + w * 2304);  // [16][72]/wave

        const int bq = blockIdx.x;          // 0..63
        const int a  = bq >> 1;             // 64-tile index
        const int q0 = bq * 32;
        const int qg = w & 1;
        const int ks = w >> 1;
        const int qi = q0 + qg * 16 + l15;  // this lane's query

        // stage Q tile (32 rows x 8 uint4)
        {
            const int row = tid >> 3, c8 = tid & 7;
            *(uint4*)&Qs[row * 72 + c8 * 8] =
                *(const uint4*)&qkv16[(size_t)(q0 + row) * (3 * HID) + h * HD + c8 * 8];
        }

        const int t0g  = max(a - 2, 0);
        const int t1g  = min(a + 2, SEQ / 64 - 1);
        const int ntot = (t1g - t0g + 1) + 1;   // window tiles + gather
        const int n0   = (ntot + 1) >> 1;       // pair0 count (all window)
        const int n1   = ntot - n0;             // pair1 count (incl. gather)

        float mq = -1.0e30f, lq = 0.f;
        f32x4 Oacc[4];
        #pragma unroll
        for (int jt = 0; jt < 4; ++jt) Oacc[jt] = (f32x4){0.f, 0.f, 0.f, 0.f};

        auto stage_tile = [&](ushort_t* Kb, ushort_t* Vb, int tile, bool gather) {
            const int nf = gather ? 256 : 512;
            for (int f = tid; f < nf; f += 256) {
                const int row = f >> 3, c8 = f & 7;
                const size_t gb = (size_t)(gather ? (row << 6) : (tile * 64 + row))
                                      * (3 * HID) + HID + h * HD + c8 * 8;
                *(uint4*)&Kb[row * 72 + c8 * 8] = *(const uint4*)&qkv16[gb];
            }
            for (int f = tid; f < nf; f += 256) {
                const int kp = f >> 4, dc = f & 15;
                const int k0i = 2 * kp, k1i = 2 * kp + 1;
                const size_t b0 = (size_t)(gather ? (k0i << 6) : (tile * 64 + k0i))
                                      * (3 * HID) + 2 * HID + h * HD + dc * 4;
                const size_t b1 = (size_t)(gather ? (k1i << 6) : (tile * 64 + k1i))
                                      * (3 * HID) + 2 * HID + h * HD + dc * 4;
                uint2 va = *(const uint2*)&qkv16[b0];
                uint2 vb = *(const uint2*)&qkv16[b1];
                unsigned int w0 = (va.x & 0xFFFFu) | (vb.x << 16);
                unsigned int w1 = (va.x >> 16)     | (vb.x & 0xFFFF0000u);
                unsigned int w2 = (va.y & 0xFFFFu) | (vb.y << 16);
                unsigned int w3 = (va.y >> 16)     | (vb.y & 0xFFFF0000u);
                *(unsigned int*)&Vb[(dc * 4 + 0) * 72 + 2 * kp] = w0;
                *(unsigned int*)&Vb[(dc * 4 + 1) * 72 + 2 * kp] = w1;
                *(unsigned int*)&Vb[(dc * 4 + 2) * 72 + 2 * kp] = w2;
                *(unsigned int*)&Vb[(dc * 4 + 3) * 72 + 2 * kp] = w3;
            }
        };

        for (int s = 0; s < n0; ++s) {
            __syncthreads();
            // stage pair0 tile (always window) and pair1 tile (if any)
            stage_tile(Kb0, Vb0, t0g + s, false);
            if (s < n1)
                stage_tile(Kb1, Vb1, t0g + n0 + s, (n0 + s) == ntot - 1);
            __syncthreads();

            const int  idx    = (ks == 0) ? s : n0 + s;
            const bool active = (ks == 0) || (s < n1);
            if (active) {
                const bool gather = (idx == ntot - 1);
                const int  tile   = t0g + idx;
                ushort_t* Kb = ks ? Kb1 : Kb0;
                ushort_t* Vb = ks ? Vb1 : Vb0;

                // ---- S^T = K @ Q^T ----
                short8 bQ0 = *(const short8*)&Qs[(qg * 16 + l15) * 72 + quad * 8];
                short8 bQ1 = *(const short8*)&Qs[(qg * 16 + l15) * 72 + 32 + quad * 8];
                f32x4 st[4];
                #pragma unroll
                for (int kt = 0; kt < 4; ++kt) {
                    short8 aK0 = *(const short8*)&Kb[(kt * 16 + l15) * 72 + quad * 8];
                    short8 aK1 = *(const short8*)&Kb[(kt * 16 + l15) * 72 + 32 + quad * 8];
                    f32x4 z = (f32x4){0.f, 0.f, 0.f, 0.f};
                    z = __builtin_amdgcn_mfma_f32_16x16x32_bf16(aK0, bQ0, z, 0, 0, 0);
                    z = __builtin_amdgcn_mfma_f32_16x16x32_bf16(aK1, bQ1, z, 0, 0, 0);
                    st[kt] = z;
                }

                // ---- mask + scale ----
                float sv[4][4];
                float tm = -1.0e30f;
                #pragma unroll
                for (int kt = 0; kt < 4; ++kt)
                    #pragma unroll
                    for (int reg = 0; reg < 4; ++reg) {
                        const int c = kt * 16 + quad * 4 + reg;
                        const int j = gather ? (c << 6) : (tile * 64 + c);
                        const bool valid = gather ? ((c < 32) && (abs(qi - j) > WIN))
                                                  : (abs(qi - j) <= WIN);
                        sv[kt][reg] = valid ? st[kt][reg] * 0.125f : -1.0e30f;
                        tm = fmaxf(tm, sv[kt][reg]);
                    }

                // ---- online softmax (reduce over quads) ----
                tm = fmaxf(tm, __shfl_xor(tm, 16));
                tm = fmaxf(tm, __shfl_xor(tm, 32));
                const float mn = fmaxf(mq, tm);
                const float alpha = __expf(mq - mn);
                float p[4][4];
                float ts = 0.f;
                #pragma unroll
                for (int kt = 0; kt < 4; ++kt)
                    #pragma unroll
                    for (int reg = 0; reg < 4; ++reg) {
                        p[kt][reg] = __expf(sv[kt][reg] - mn);
                        ts += p[kt][reg];
                    }
                ts += __shfl_xor(ts, 16);
                ts += __shfl_xor(ts, 32);
                lq = lq * alpha + ts;
                mq = mn;

                // ---- P -> wave-private LDS ----
                #pragma unroll
                for (int kt = 0; kt < 4; ++kt) {
                    ushort4 pkt;
                    pkt.x = bf16b(p[kt][0]); pkt.y = bf16b(p[kt][1]);
                    pkt.z = bf16b(p[kt][2]); pkt.w = bf16b(p[kt][3]);
                    *(ushort4*)&Psw[l15 * 72 + kt * 16 + quad * 4] = pkt;
                }
                #pragma unroll
                for (int jt = 0; jt < 4; ++jt) {
                    Oacc[jt][0] *= alpha; Oacc[jt][1] *= alpha;
                    Oacc[jt][2] *= alpha; Oacc[jt][3] *= alpha;
                }

                // ---- O^T += V^T @ P^T ----
                short8 bP0 = *(const short8*)&Psw[l15 * 72 + quad * 8];
                short8 bP1 = *(const short8*)&Psw[l15 * 72 + 32 + quad * 8];
                #pragma unroll
                for (int jt = 0; jt < 4; ++jt) {
                    short8 aV0 = *(const short8*)&Vb[(jt * 16 + l15) * 72 + quad * 8];
                    short8 aV1 = *(const short8*)&Vb[(jt * 16 + l15) * 72 + 32 + quad * 8];
                    Oacc[jt] = __builtin_amdgcn_mfma_f32_16x16x32_bf16(aV0, bP0, Oacc[jt], 0, 0, 0);
                    Oacc[jt] = __builtin_amdgcn_mfma_f32_16x16x32_bf16(aV1, bP1, Oacc[jt], 0, 0, 0);
                }
            }
        }

        // ---- 2-way merge across key-splits via LDS ----
        __syncthreads();
        float* Om = (float*)smem;              // [2][32][64] = 16384 B
        float* Ml = (float*)(smem + 16384);    // [2][32]
        float* Ll = (float*)(smem + 16640);    // [2][32]
        #pragma unroll
        for (int jt = 0; jt < 4; ++jt) {
            float4 v = make_float4(Oacc[jt][0], Oacc[jt][1], Oacc[jt][2], Oacc[jt][3]);
            *(float4*)&Om[(ks * 32 + qg * 16 + l15) * 64 + jt * 16 + quad * 4] = v;
        }
        if (quad == 0) { Ml[ks * 32 + qg * 16 + l15] = mq; Ll[ks * 32 + qg * 16 + l15] = lq; }
        __syncthreads();

        {
            const int q  = tid >> 3;            // 0..31
            const int dc = (tid & 7) * 8;       // dim chunk
            const int iq = q0 + q;
            if ((iq & 63) != 0) {               // skip global rows
                const float m0 = Ml[q], m1 = Ml[32 + q];
                const float mM = fmaxf(m0, m1);
                const float e0 = __expf(m0 - mM), e1 = __expf(m1 - mM);
                const float inv = 1.0f / (e0 * Ll[q] + e1 * Ll[32 + q]);
                ushort4 oa, ob;
                float o0 = (e0 * Om[q * 64 + dc + 0] + e1 * Om[(32 + q) * 64 + dc + 0]) * inv;
                float o1 = (e0 * Om[q * 64 + dc + 1] + e1 * Om[(32 + q) * 64 + dc + 1]) * inv;
                float o2 = (e0 * Om[q * 64 + dc + 2] + e1 * Om[(32 + q) * 64 + dc + 2]) * inv;
                float o3 = (e0 * Om[q * 64 + dc + 3] + e1 * Om[(32 + q) * 64 + dc + 3]) * inv;
                float o4 = (e0 * Om[q * 64 + dc + 4] + e1 * Om[(32 + q) * 64 + dc + 4]) * inv;
                float o5 = (e0 * Om[q * 64 + dc + 5] + e1 * Om[(32 + q) * 64 + dc + 5]) * inv;
                float o6 = (e0 * Om[q * 64 + dc + 6] + e1 * Om[(32 + q) * 64 + dc + 6]) * inv;
                float o7 = (e0 * Om[q * 64 + dc + 7] + e1 * Om[(32 + q) * 64 + dc + 7]) * inv;
                oa.x = bf16b(o0); oa.y = bf16b(o1); oa.z = bf16b(o2); oa.w = bf16b(o3);
                ob.x = bf16b(o4); ob.y = bf16b(o5); ob.z = bf16b(o6); ob.w = bf16b(o7);
                *(ushort4*)&aout16[(size_t)iq * HID + h * HD + dc]     = oa;
                *(ushort4*)&aout16[(size_t)iq * HID + h * HD + dc + 4] = ob;
            }
        }
    } else {
        // ----------------- global-row path (MFMA flash-decoding) -----------
        const int gh = blockIdx.x - 64;   // 0 or 1
        ushort_t* Ksw = (ushort_t*)(smem + w * 9728);
        ushort_t* Vtw = (ushort_t*)(smem + w * 9728 + 4608);
        ushort_t* Psw = (ushort_t*)(smem + w * 9728 + 8704);

        const size_t qrow = (size_t)((gh * 16 + l15) * 64) * (3 * HID) + h * HD;
        short8 bQ0 = *(const short8*)&qkv16[qrow + quad * 8];
        short8 bQ1 = *(const short8*)&qkv16[qrow + 32 + quad * 8];

        float mq = -1.0e30f, lq = 0.f;
        f32x4 Oacc[4];
        #pragma unroll
        for (int jt = 0; jt < 4; ++jt) Oacc[jt] = (f32x4){0.f, 0.f, 0.f, 0.f};

        for (int s = 0; s < 16; ++s) {
            const int kb = w * 512 + s * 32;
            #pragma unroll
            for (int u = 0; u < 4; ++u) {
                const int unit = lane + u * 64;
                const int row = unit >> 3, c8 = unit & 7;
                *(uint4*)&Ksw[row * 72 + c8 * 8] =
                    *(const uint4*)&qkv16[(size_t)(kb + row) * (3 * HID) + HID + h * HD + c8 * 8];
            }
            #pragma unroll
            for (int u = 0; u < 4; ++u) {
                const int unit = lane + u * 64;
                const int kp = unit >> 4, dc = unit & 15;
                const size_t b0 = (size_t)(kb + 2 * kp) * (3 * HID) + 2 * HID + h * HD + dc * 4;
                const size_t b1 = b0 + 3 * HID;
                uint2 va = *(const uint2*)&qkv16[b0];
                uint2 vb = *(const uint2*)&qkv16[b1];
                unsigned int w0 = (va.x & 0xFFFFu) | (vb.x << 16);
                unsigned int w1 = (va.x >> 16)     | (vb.x & 0xFFFF0000u);
                unsigned int w2 = (va.y & 0xFFFFu) | (vb.y << 16);
                unsigned int w3 = (va.y >> 16)     | (vb.y & 0xFFFF0000u);
                *(unsigned int*)&Vtw[(dc * 4 + 0) * 32 + 2 * kp] = w0;
                *(unsigned int*)&Vtw[(dc * 4 + 1) * 32 + 2 * kp] = w1;
                *(unsigned int*)&Vtw[(dc * 4 + 2) * 32 + 2 * kp] = w2;
                *(unsigned int*)&Vtw[(dc * 4 + 3) * 32 + 2 * kp] = w3;
            }

            f32x4 st[2];
            #pragma unroll
            for (int kt = 0; kt < 2; ++kt) {
                short8 aK0 = *(const short8*)&Ksw[(kt * 16 + l15) * 72 + quad * 8];
                short8 aK1 = *(const short8*)&Ksw[(kt * 16 + l15) * 72 + 32 + quad * 8];
                f32x4 z = (f32x4){0.f, 0.f, 0.f, 0.f};
                z = __builtin_amdgcn_mfma_f32_16x16x32_bf16(aK0, bQ0, z, 0, 0, 0);
                z = __builtin_amdgcn_mfma_f32_16x16x32_bf16(aK1, bQ1, z, 0, 0, 0);
                st[kt] = z;
            }

            float sv[2][4];
            float tm = -1.0e30f;
            #pragma unroll
            for (int kt = 0; kt < 2; ++kt)
                #pragma unroll
                for (int reg = 0; reg < 4; ++reg) {
                    sv[kt][reg] = st[kt][reg] * 0.125f;
                    tm = fmaxf(tm, sv[kt][reg]);
                }
            tm = fmaxf(tm, __shfl_xor(tm, 16));
            tm = fmaxf(tm, __shfl_xor(tm, 32));
            const float mn = fmaxf(mq, tm);
            const float alpha = __expf(mq - mn);
            float p[2][4];
            float ts = 0.f;
            #pragma unroll
            for (int kt = 0; kt < 2; ++kt)
                #pragma unroll
                for (int reg = 0; reg < 4; ++reg) {
                    p[kt][reg] = __expf(sv[kt][reg] - mn);
                    ts += p[kt][reg];
                }
            ts += __shfl_xor(ts, 16);
            ts += __shfl_xor(ts, 32);
            lq = lq * alpha + ts;
            mq = mn;

            #pragma unroll
            for (int kt = 0; kt < 2; ++kt) {
                ushort4 pkt;
                pkt.x = bf16b(p[kt][0]); pkt.y = bf16b(p[kt][1]);
                pkt.z = bf16b(p[kt][2]); pkt.w = bf16b(p[kt][3]);
                *(ushort4*)&Psw[l15 * 32 + kt * 16 + quad * 4] = pkt;
            }
            #pragma unroll
            for (int jt = 0; jt < 4; ++jt) {
                Oacc[jt][0] *= alpha; Oacc[jt][1] *= alpha;
                Oacc[jt][2] *= alpha; Oacc[jt][3] *= alpha;
            }

            short8 bP = *(const short8*)&Psw[l15 * 32 + quad * 8];
            #pragma unroll
            for (int jt = 0; jt < 4; ++jt) {
                short8 aV = *(const short8*)&Vtw[(jt * 16 + l15) * 32 + quad * 8];
                Oacc[jt] = __builtin_amdgcn_mfma_f32_16x16x32_bf16(aV, bP, Oacc[jt], 0, 0, 0);
            }
        }

        __syncthreads();
        float* Om = (float*)smem;              // [4][16][64]
        float* Ml = (float*)(smem + 16384);    // [4][16]
        float* Ll = (float*)(smem + 16640);    // [4][16]
        #pragma unroll
        for (int jt = 0; jt < 4; ++jt)
            #pragma unroll
            for (int reg = 0; reg < 4; ++reg)
                Om[(w * 16 + l15) * 64 + jt * 16 + quad * 4 + reg] = Oacc[jt][reg];
        if (quad == 0) { Ml[w * 16 + l15] = mq; Ll[w * 16 + l15] = lq; }
        __syncthreads();

        const int d = tid & 63;
        #pragma unroll
        for (int k = 0; k < 4; ++k) {
            const int q = (tid >> 6) * 4 + k;
            float m0 = Ml[q], m1 = Ml[16 + q], m2 = Ml[32 + q], m3 = Ml[48 + q];
            float mM = fmaxf(fmaxf(m0, m1), fmaxf(m2, m3));
            float e0 = __expf(m0 - mM), e1 = __expf(m1 - mM);
            float e2 = __expf(m2 - mM), e3 = __expf(m3 - mM);
            float l = e0 * Ll[q] + e1 * Ll[16 + q] + e2 * Ll[32 + q] + e3 * Ll[48 + q];
            float o = e0 * Om[(q) * 64 + d]        + e1 * Om[(16 + q) * 64 + d]
                    + e2 * Om[(32 + q) * 64 + d]   + e3 * Om[(48 + q) * 64 + d];
            const int i = (gh * 16 + q) * 64;
            aout16[(size_t)i * HID + h * HD + d] = bf16b(o / l);
        }
    }
}

extern "C" void kernel_launch(void* const* d_in, const int* in_sizes, int n_in,
                              void* d_out, int out_size, void* d_ws, size_t ws_size,
                              hipStream_t stream) {
    const float* x    = (const float*)d_in[0];   // [2048,1024] fp32
    const float* Wqkv = (const float*)d_in[1];   // [3072,1024] fp32
    const float* Wout = (const float*)d_in[2];   // [1024,1024] fp32
    float* out = (float*)d_out;                  // [2048,1024] fp32

    unsigned short* x16    = (unsigned short*)d_ws;                 // 2048*1024
    unsigned short* wq16   = x16  + (size_t)SEQ * HID;              // 3072*1024
    unsigned short* wo16   = wq16 + (size_t)3 * HID * HID;          // 1024*1024
    unsigned short* qkv16  = wo16 + (size_t)HID * HID;              // 2048*3072
    unsigned short* aout16 = qkv16 + (size_t)SEQ * 3 * HID;         // 2048*1024

    // 0) fp32 -> bf16 conversions
    cvt_bf16<<<dim3(1024), 256, 0, stream>>>(
        (const float4*)x, (const float4*)Wqkv, (const float4*)Wout,
        (ushort4*)x16, (ushort4*)wq16, (ushort4*)wo16);

    // 1) qkv16 = x16 @ wq16^T  (bf16 out): 64x128 tile -> 768 blocks (3/CU)
    gemm_bt16<64, 128, unsigned short><<<dim3(3 * HID / 128, SEQ / 64), 256, 0, stream>>>(
        x16, wq16, qkv16, SEQ, 3 * HID, HID);

    // 2) fused banded (32-q key-split) + global (MFMA flash-decoding)
    attn_fused<<<dim3(66, NH), 256, 0, stream>>>(qkv16, aout16);

    // 3) out = aout16 @ wo16^T  (fp32 out): 64x64 tile -> 512 blocks (2/CU)
    gemm_bt16<64, 64, float><<<dim3(HID / 64, SEQ / 64), 256, 0, stream>>>(
        aout16, wo16, out, SEQ, HID, HID);
}

// Round 12
// 146.433 us; speedup vs baseline: 1.0894x; 1.0894x over previous
//
#include <hip/hip_runtime.h>
#include <hip/hip_bf16.h>
#include <math.h>

// Problem constants (B=1)
#define SEQ   2048
#define HID   1024
#define NH    16
#define HD    64
#define WIN   128
#define GSTR  64

typedef __attribute__((ext_vector_type(8))) short short8;   // 8 bf16 = 4 VGPRs
typedef __attribute__((ext_vector_type(4))) float f32x4;    // MFMA C/D
typedef unsigned short ushort_t;

// RNE fp32 -> bf16 bits (finite inputs)
__device__ inline unsigned short bf16b(float f) {
    union { float f; unsigned int u; } v; v.f = f;
    return (unsigned short)((v.u + 0x7FFFu + ((v.u >> 16) & 1u)) >> 16);
}
// bf16 (low/high ushort of a uint) -> fp32
__device__ inline float blo(unsigned int u) {
    union { unsigned int i; float f; } v; v.i = u << 16; return v.f;
}
__device__ inline float bhi(unsigned int u) {
    union { unsigned int i; float f; } v; v.i = u & 0xFFFF0000u; return v.f;
}

#define GLOAD_LDS16(gp, lp)                                                    \
    __builtin_amdgcn_global_load_lds(                                          \
        (const __attribute__((address_space(1))) unsigned int*)(gp),           \
        (__attribute__((address_space(3))) unsigned int*)(lp), 16, 0, 0)

// ---------------------------------------------------------------------------
// fp32 -> bf16 pre-convert of x, Wqkv, Wout
// ---------------------------------------------------------------------------
__global__ __launch_bounds__(256) void cvt_bf16(const float4* __restrict__ x,
                                                const float4* __restrict__ wq,
                                                const float4* __restrict__ wo,
                                                ushort4* __restrict__ x16,
                                                ushort4* __restrict__ wq16,
                                                ushort4* __restrict__ wo16) {
    for (int idx = blockIdx.x * 256 + threadIdx.x; idx < 1572864;
         idx += gridDim.x * 256) {
        const float4* src; ushort4* dst; int off;
        if (idx < 524288)       { src = x;  dst = x16;  off = idx; }
        else if (idx < 1310720) { src = wq; dst = wq16; off = idx - 524288; }
        else                    { src = wo; dst = wo16; off = idx - 1310720; }
        float4 v = src[off];
        ushort4 o;
        o.x = bf16b(v.x); o.y = bf16b(v.y); o.z = bf16b(v.z); o.w = bf16b(v.w);
        dst[off] = o;
    }
}

// ---------------------------------------------------------------------------
// MFMA GEMM: C[M,N] = A[M,K] @ B[N,K]^T, bf16 in, fp32 acc.
// Tile BM x BN, BK=64 as TWO stacked 32-col panels (each panel identical to
// the validated BK=32 layout; lane-contiguous for global_load_lds).
// Halves barrier count vs BK=32 — the barrier drain dominates at this shape.
// 256 threads (4 waves, 2x2 wave grid).
// ---------------------------------------------------------------------------
template <int BM, int BN, typename OT>
__global__ __launch_bounds__(256) void gemm_bt16(const unsigned short* __restrict__ A,
                                                 const unsigned short* __restrict__ B,
                                                 OT* __restrict__ C,
                                                 int M, int N, int K) {
    constexpr int MI = BM / 32;
    constexpr int NJ = BN / 32;
    __shared__ unsigned short As[2][BM * 32];
    __shared__ unsigned short Bs[2][BN * 32];

    const int tid  = threadIdx.x;
    const int wave = tid >> 6;
    const int lane = tid & 63;
    const int quad = lane >> 4;
    const int l15  = lane & 15;
    const int bm = blockIdx.y * BM;
    const int bn = blockIdx.x * BN;
    const int wm = (wave & 1) * (BM / 2);
    const int wn = (wave >> 1) * (BN / 2);
    const int srow = lane >> 2;
    const int scol = (lane & 3) * 8;

    f32x4 acc[MI][NJ];
    #pragma unroll
    for (int i = 0; i < MI; ++i)
        #pragma unroll
        for (int j = 0; j < NJ; ++j)
            acc[i][j] = (f32x4){0.f, 0.f, 0.f, 0.f};

    for (int k0 = 0; k0 < K; k0 += 64) {
        #pragma unroll
        for (int hh = 0; hh < 2; ++hh) {
            #pragma unroll
            for (int t = 0; t < BM / 64; ++t) {
                const int row = wave * (BM / 4) + t * 16 + srow;
                GLOAD_LDS16(A + (size_t)(bm + row) * K + k0 + hh * 32 + scol,
                            &As[hh][(size_t)row * 32 + scol]);
            }
            #pragma unroll
            for (int t = 0; t < BN / 64; ++t) {
                const int row = wave * (BN / 4) + t * 16 + srow;
                GLOAD_LDS16(B + (size_t)(bn + row) * K + k0 + hh * 32 + scol,
                            &Bs[hh][(size_t)row * 32 + scol]);
            }
        }
        __syncthreads();

        #pragma unroll
        for (int hh = 0; hh < 2; ++hh) {
            short8 a[MI], b[NJ];
            #pragma unroll
            for (int im = 0; im < MI; ++im)
                a[im] = *(const short8*)&As[hh][(wm + im * 16 + l15) * 32 + quad * 8];
            #pragma unroll
            for (int jn = 0; jn < NJ; ++jn)
                b[jn] = *(const short8*)&Bs[hh][(wn + jn * 16 + l15) * 32 + quad * 8];

            #pragma unroll
            for (int im = 0; im < MI; ++im)
                #pragma unroll
                for (int jn = 0; jn < NJ; ++jn)
                    acc[im][jn] = __builtin_amdgcn_mfma_f32_16x16x32_bf16(
                        a[im], b[jn], acc[im][jn], 0, 0, 0);
        }
        __syncthreads();
    }

    #pragma unroll
    for (int im = 0; im < MI; ++im)
        #pragma unroll
        for (int jn = 0; jn < NJ; ++jn)
            #pragma unroll
            for (int reg = 0; reg < 4; ++reg) {
                const int r = bm + wm + im * 16 + quad * 4 + reg;
                const int c = bn + wn + jn * 16 + l15;
                float v = acc[im][jn][reg];
                if constexpr (sizeof(OT) == 2)
                    C[(size_t)r * N + c] = (OT)bf16b(v);
                else
                    C[(size_t)r * N + c] = (OT)v;
            }
}

// ---------------------------------------------------------------------------
// Fused attention (REVERTED to the R10/best-measured version).
// blockIdx.x < 32: banded+gather flash tile (S^T MFMA + register prefetch).
// blockIdx.x in {32,33}: global rows, MFMA flash-decoding.
// ---------------------------------------------------------------------------
__global__ __launch_bounds__(256) void attn_fused(const unsigned short* __restrict__ qkv16,
                                                  unsigned short* __restrict__ aout16) {
    __shared__ __align__(16) unsigned char smem[38912];
    const int tid = threadIdx.x;
    const int h = blockIdx.y;
    const int w    = tid >> 6;
    const int lane = tid & 63;
    const int quad = lane >> 4;
    const int l15  = lane & 15;

    if (blockIdx.x < 32) {
        // ----------------- banded path (S^T MFMA + prefetch) -----------------
        ushort_t* Qs = (ushort_t*)smem;              // [64][72] bf16, 9216 B
        ushort_t* Ks = (ushort_t*)(smem + 9216);     // [64][72]
        ushort_t* Vt = (ushort_t*)(smem + 18432);    // [64][72]  Vt[d][key]
        ushort_t* Ps = (ushort_t*)(smem + 27648);    // [64][72]  Ps[q][key]

        const int bq = blockIdx.x;
        const int q0 = bq * 64;
        const int qi = q0 + w * 16 + l15;   // this lane's query

        for (int f = tid; f < 512; f += 256) {
            int row = f >> 3, c8 = f & 7;
            *(uint4*)&Qs[row * 72 + c8 * 8] =
                *(const uint4*)&qkv16[(size_t)(q0 + row) * (3 * HID) + h * HD + c8 * 8];
        }

        float mq = -1.0e30f, lq = 0.f;
        f32x4 Oacc[4];
        #pragma unroll
        for (int jt = 0; jt < 4; ++jt) Oacc[jt] = (f32x4){0.f, 0.f, 0.f, 0.f};

        const int t0 = max(bq - 2, 0);
        const int t1 = min(bq + 2, SEQ / 64 - 1);

        uint4 pk[2];
        uint2 pva[2], pvb[2];

        auto prefetch = [&](int tt2, bool g2) {
            const int nf = g2 ? 256 : 512;
            #pragma unroll
            for (int u = 0; u < 2; ++u) {
                const int f = tid + u * 256;
                if (f < nf) {
                    const int row = f >> 3, c8 = f & 7;
                    const size_t gb = (size_t)(g2 ? (row << 6) : (tt2 * 64 + row))
                                          * (3 * HID) + HID + h * HD + c8 * 8;
                    pk[u] = *(const uint4*)&qkv16[gb];
                    const int kp = f >> 4, dc = f & 15;
                    const int k0i = 2 * kp, k1i = 2 * kp + 1;
                    const size_t b0 = (size_t)(g2 ? (k0i << 6) : (tt2 * 64 + k0i))
                                          * (3 * HID) + 2 * HID + h * HD + dc * 4;
                    const size_t b1 = (size_t)(g2 ? (k1i << 6) : (tt2 * 64 + k1i))
                                          * (3 * HID) + 2 * HID + h * HD + dc * 4;
                    pva[u] = *(const uint2*)&qkv16[b0];
                    pvb[u] = *(const uint2*)&qkv16[b1];
                }
            }
        };
        auto commit = [&](bool g2) {
            const int nf = g2 ? 256 : 512;
            #pragma unroll
            for (int u = 0; u < 2; ++u) {
                const int f = tid + u * 256;
                if (f < nf) {
                    const int row = f >> 3, c8 = f & 7;
                    *(uint4*)&Ks[row * 72 + c8 * 8] = pk[u];
                    const int kp = f >> 4, dc = f & 15;
                    uint2 va = pva[u], vb = pvb[u];
                    unsigned int w0 = (va.x & 0xFFFFu) | (vb.x << 16);
                    unsigned int w1 = (va.x >> 16)     | (vb.x & 0xFFFF0000u);
                    unsigned int w2 = (va.y & 0xFFFFu) | (vb.y << 16);
                    unsigned int w3 = (va.y >> 16)     | (vb.y & 0xFFFF0000u);
                    *(unsigned int*)&Vt[(dc * 4 + 0) * 72 + 2 * kp] = w0;
                    *(unsigned int*)&Vt[(dc * 4 + 1) * 72 + 2 * kp] = w1;
                    *(unsigned int*)&Vt[(dc * 4 + 2) * 72 + 2 * kp] = w2;
                    *(unsigned int*)&Vt[(dc * 4 + 3) * 72 + 2 * kp] = w3;
                }
            }
        };

        prefetch(t0, false);
        commit(false);
        __syncthreads();

        for (int tt = t0; tt <= t1 + 1; ++tt) {
            const bool gather = (tt == t1 + 1);
            const bool hasnext = (tt < t1 + 1);
            if (hasnext) prefetch(tt + 1, (tt + 1) == t1 + 1);

            short8 bQ0 = *(const short8*)&Qs[(w * 16 + l15) * 72 + quad * 8];
            short8 bQ1 = *(const short8*)&Qs[(w * 16 + l15) * 72 + 32 + quad * 8];
            f32x4 st[4];
            #pragma unroll
            for (int kt = 0; kt < 4; ++kt) {
                short8 aK0 = *(const short8*)&Ks[(kt * 16 + l15) * 72 + quad * 8];
                short8 aK1 = *(const short8*)&Ks[(kt * 16 + l15) * 72 + 32 + quad * 8];
                f32x4 z = (f32x4){0.f, 0.f, 0.f, 0.f};
                z = __builtin_amdgcn_mfma_f32_16x16x32_bf16(aK0, bQ0, z, 0, 0, 0);
                z = __builtin_amdgcn_mfma_f32_16x16x32_bf16(aK1, bQ1, z, 0, 0, 0);
                st[kt] = z;
            }

            float sv[4][4];
            float tm = -1.0e30f;
            #pragma unroll
            for (int kt = 0; kt < 4; ++kt)
                #pragma unroll
                for (int reg = 0; reg < 4; ++reg) {
                    const int c = kt * 16 + quad * 4 + reg;
                    const int j = gather ? (c << 6) : (tt * 64 + c);
                    const bool valid = gather ? ((c < 32) && (abs(qi - j) > WIN))
                                              : (abs(qi - j) <= WIN);
                    sv[kt][reg] = valid ? st[kt][reg] * 0.125f : -1.0e30f;
                    tm = fmaxf(tm, sv[kt][reg]);
                }

            tm = fmaxf(tm, __shfl_xor(tm, 16));
            tm = fmaxf(tm, __shfl_xor(tm, 32));
            const float mn = fmaxf(mq, tm);
            const float alpha = __expf(mq - mn);
            float p[4][4];
            float ts = 0.f;
            #pragma unroll
            for (int kt = 0; kt < 4; ++kt)
                #pragma unroll
                for (int reg = 0; reg < 4; ++reg) {
                    p[kt][reg] = __expf(sv[kt][reg] - mn);
                    ts += p[kt][reg];
                }
            ts += __shfl_xor(ts, 16);
            ts += __shfl_xor(ts, 32);
            lq = lq * alpha + ts;
            mq = mn;

            #pragma unroll
            for (int kt = 0; kt < 4; ++kt) {
                ushort4 pkt;
                pkt.x = bf16b(p[kt][0]); pkt.y = bf16b(p[kt][1]);
                pkt.z = bf16b(p[kt][2]); pkt.w = bf16b(p[kt][3]);
                *(ushort4*)&Ps[(w * 16 + l15) * 72 + kt * 16 + quad * 4] = pkt;
            }
            #pragma unroll
            for (int jt = 0; jt < 4; ++jt) {
                Oacc[jt][0] *= alpha; Oacc[jt][1] *= alpha;
                Oacc[jt][2] *= alpha; Oacc[jt][3] *= alpha;
            }

            short8 bP0 = *(const short8*)&Ps[(w * 16 + l15) * 72 + quad * 8];
            short8 bP1 = *(const short8*)&Ps[(w * 16 + l15) * 72 + 32 + quad * 8];
            #pragma unroll
            for (int jt = 0; jt < 4; ++jt) {
                short8 aV0 = *(const short8*)&Vt[(jt * 16 + l15) * 72 + quad * 8];
                short8 aV1 = *(const short8*)&Vt[(jt * 16 + l15) * 72 + 32 + quad * 8];
                Oacc[jt] = __builtin_amdgcn_mfma_f32_16x16x32_bf16(aV0, bP0, Oacc[jt], 0, 0, 0);
                Oacc[jt] = __builtin_amdgcn_mfma_f32_16x16x32_bf16(aV1, bP1, Oacc[jt], 0, 0, 0);
            }

            if (hasnext) {
                __syncthreads();
                commit((tt + 1) == t1 + 1);
                __syncthreads();
            }
        }

        if (!(w == 0 && l15 == 0)) {   // skip global rows (qi % 64 == 0)
            const float inv = 1.0f / lq;
            #pragma unroll
            for (int jt = 0; jt < 4; ++jt) {
                ushort4 o;
                o.x = bf16b(Oacc[jt][0] * inv);
                o.y = bf16b(Oacc[jt][1] * inv);
                o.z = bf16b(Oacc[jt][2] * inv);
                o.w = bf16b(Oacc[jt][3] * inv);
                *(ushort4*)&aout16[(size_t)qi * HID + h * HD + jt * 16 + quad * 4] = o;
            }
        }
    } else {
        // ----------------- global-row path (MFMA flash-decoding) -----------
        const int gh = blockIdx.x - 32;   // 0 or 1
        ushort_t* Ksw = (ushort_t*)(smem + w * 9728);
        ushort_t* Vtw = (ushort_t*)(smem + w * 9728 + 4608);
        ushort_t* Psw = (ushort_t*)(smem + w * 9728 + 8704);

        const size_t qrow = (size_t)((gh * 16 + l15) * 64) * (3 * HID) + h * HD;
        short8 bQ0 = *(const short8*)&qkv16[qrow + quad * 8];
        short8 bQ1 = *(const short8*)&qkv16[qrow + 32 + quad * 8];

        float mq = -1.0e30f, lq = 0.f;
        f32x4 Oacc[4];
        #pragma unroll
        for (int jt = 0; jt < 4; ++jt) Oacc[jt] = (f32x4){0.f, 0.f, 0.f, 0.f};

        for (int s = 0; s < 16; ++s) {
            const int kb = w * 512 + s * 32;
            #pragma unroll
            for (int u = 0; u < 4; ++u) {
                const int unit = lane + u * 64;
                const int row = unit >> 3, c8 = unit & 7;
                *(uint4*)&Ksw[row * 72 + c8 * 8] =
                    *(const uint4*)&qkv16[(size_t)(kb + row) * (3 * HID) + HID + h * HD + c8 * 8];
            }
            #pragma unroll
            for (int u = 0; u < 4; ++u) {
                const int unit = lane + u * 64;
                const int kp = unit >> 4, dc = unit & 15;
                const size_t b0 = (size_t)(kb + 2 * kp) * (3 * HID) + 2 * HID + h * HD + dc * 4;
                const size_t b1 = b0 + 3 * HID;
                uint2 va = *(const uint2*)&qkv16[b0];
                uint2 vb = *(const uint2*)&qkv16[b1];
                unsigned int w0 = (va.x & 0xFFFFu) | (vb.x << 16);
                unsigned int w1 = (va.x >> 16)     | (vb.x & 0xFFFF0000u);
                unsigned int w2 = (va.y & 0xFFFFu) | (vb.y << 16);
                unsigned int w3 = (va.y >> 16)     | (vb.y & 0xFFFF0000u);
                *(unsigned int*)&Vtw[(dc * 4 + 0) * 32 + 2 * kp] = w0;
                *(unsigned int*)&Vtw[(dc * 4 + 1) * 32 + 2 * kp] = w1;
                *(unsigned int*)&Vtw[(dc * 4 + 2) * 32 + 2 * kp] = w2;
                *(unsigned int*)&Vtw[(dc * 4 + 3) * 32 + 2 * kp] = w3;
            }

            f32x4 st[2];
            #pragma unroll
            for (int kt = 0; kt < 2; ++kt) {
                short8 aK0 = *(const short8*)&Ksw[(kt * 16 + l15) * 72 + quad * 8];
                short8 aK1 = *(const short8*)&Ksw[(kt * 16 + l15) * 72 + 32 + quad * 8];
                f32x4 z = (f32x4){0.f, 0.f, 0.f, 0.f};
                z = __builtin_amdgcn_mfma_f32_16x16x32_bf16(aK0, bQ0, z, 0, 0, 0);
                z = __builtin_amdgcn_mfma_f32_16x16x32_bf16(aK1, bQ1, z, 0, 0, 0);
                st[kt] = z;
            }

            float sv[2][4];
            float tm = -1.0e30f;
            #pragma unroll
            for (int kt = 0; kt < 2; ++kt)
                #pragma unroll
                for (int reg = 0; reg < 4; ++reg) {
                    sv[kt][reg] = st[kt][reg] * 0.125f;
                    tm = fmaxf(tm, sv[kt][reg]);
                }
            tm = fmaxf(tm, __shfl_xor(tm, 16));
            tm = fmaxf(tm, __shfl_xor(tm, 32));
            const float mn = fmaxf(mq, tm);
            const float alpha = __expf(mq - mn);
            float p[2][4];
            float ts = 0.f;
            #pragma unroll
            for (int kt = 0; kt < 2; ++kt)
                #pragma unroll
                for (int reg = 0; reg < 4; ++reg) {
                    p[kt][reg] = __expf(sv[kt][reg] - mn);
                    ts += p[kt][reg];
                }
            ts += __shfl_xor(ts, 16);
            ts += __shfl_xor(ts, 32);
            lq = lq * alpha + ts;
            mq = mn;

            #pragma unroll
            for (int kt = 0; kt < 2; ++kt) {
                ushort4 pkt;
                pkt.x = bf16b(p[kt][0]); pkt.y = bf16b(p[kt][1]);
                pkt.z = bf16b(p[kt][2]); pkt.w = bf16b(p[kt][3]);
                *(ushort4*)&Psw[l15 * 32 + kt * 16 + quad * 4] = pkt;
            }
            #pragma unroll
            for (int jt = 0; jt < 4; ++jt) {
                Oacc[jt][0] *= alpha; Oacc[jt][1] *= alpha;
                Oacc[jt][2] *= alpha; Oacc[jt][3] *= alpha;
            }

            short8 bP = *(const short8*)&Psw[l15 * 32 + quad * 8];
            #pragma unroll
            for (int jt = 0; jt < 4; ++jt) {
                short8 aV = *(const short8*)&Vtw[(jt * 16 + l15) * 32 + quad * 8];
                Oacc[jt] = __builtin_amdgcn_mfma_f32_16x16x32_bf16(aV, bP, Oacc[jt], 0, 0, 0);
            }
        }

        __syncthreads();
        float* Om = (float*)smem;              // [4][16][64]
        float* Ml = (float*)(smem + 16384);    // [4][16]
        float* Ll = (float*)(smem + 16640);    // [4][16]
        #pragma unroll
        for (int jt = 0; jt < 4; ++jt)
            #pragma unroll
            for (int reg = 0; reg < 4; ++reg)
                Om[(w * 16 + l15) * 64 + jt * 16 + quad * 4 + reg] = Oacc[jt][reg];
        if (quad == 0) { Ml[w * 16 + l15] = mq; Ll[w * 16 + l15] = lq; }
        __syncthreads();

        const int d = tid & 63;
        #pragma unroll
        for (int k = 0; k < 4; ++k) {
            const int q = (tid >> 6) * 4 + k;
            float m0 = Ml[q], m1 = Ml[16 + q], m2 = Ml[32 + q], m3 = Ml[48 + q];
            float mM = fmaxf(fmaxf(m0, m1), fmaxf(m2, m3));
            float e0 = __expf(m0 - mM), e1 = __expf(m1 - mM);
            float e2 = __expf(m2 - mM), e3 = __expf(m3 - mM);
            float l = e0 * Ll[q] + e1 * Ll[16 + q] + e2 * Ll[32 + q] + e3 * Ll[48 + q];
            float o = e0 * Om[(q) * 64 + d]        + e1 * Om[(16 + q) * 64 + d]
                    + e2 * Om[(32 + q) * 64 + d]   + e3 * Om[(48 + q) * 64 + d];
            const int i = (gh * 16 + q) * 64;
            aout16[(size_t)i * HID + h * HD + d] = bf16b(o / l);
        }
    }
}

extern "C" void kernel_launch(void* const* d_in, const int* in_sizes, int n_in,
                              void* d_out, int out_size, void* d_ws, size_t ws_size,
                              hipStream_t stream) {
    const float* x    = (const float*)d_in[0];   // [2048,1024] fp32
    const float* Wqkv = (const float*)d_in[1];   // [3072,1024] fp32
    const float* Wout = (const float*)d_in[2];   // [1024,1024] fp32
    float* out = (float*)d_out;                  // [2048,1024] fp32

    unsigned short* x16    = (unsigned short*)d_ws;                 // 2048*1024
    unsigned short* wq16   = x16  + (size_t)SEQ * HID;              // 3072*1024
    unsigned short* wo16   = wq16 + (size_t)3 * HID * HID;          // 1024*1024
    unsigned short* qkv16  = wo16 + (size_t)HID * HID;              // 2048*3072
    unsigned short* aout16 = qkv16 + (size_t)SEQ * 3 * HID;         // 2048*1024

    // 0) fp32 -> bf16 conversions
    cvt_bf16<<<dim3(1024), 256, 0, stream>>>(
        (const float4*)x, (const float4*)Wqkv, (const float4*)Wout,
        (ushort4*)x16, (ushort4*)wq16, (ushort4*)wo16);

    // 1) qkv16 = x16 @ wq16^T  (bf16 out): 64x128 tile, BK=64 -> 768 blocks
    gemm_bt16<64, 128, unsigned short><<<dim3(3 * HID / 128, SEQ / 64), 256, 0, stream>>>(
        x16, wq16, qkv16, SEQ, 3 * HID, HID);

    // 2) fused banded (prefetch) + global (MFMA flash-decoding) attention
    attn_fused<<<dim3(34, NH), 256, 0, stream>>>(qkv16, aout16);

    // 3) out = aout16 @ wo16^T  (fp32 out): 64x64 tile, BK=64 -> 512 blocks
    gemm_bt16<64, 64, float><<<dim3(HID / 64, SEQ / 64), 256, 0, stream>>>(
        aout16, wo16, out, SEQ, HID, HID);
}